// Round 9
// baseline (174.124 us; speedup 1.0000x reference)
//
#include <hip/hip_runtime.h>
#include <hip/hip_bf16.h>
#include <math.h>

#define BB 2
#define TT 2048
#define CC 1024
#define HH 16
#define DD 64
#define C3 3072
#define BT 4096

typedef __attribute__((ext_vector_type(8))) short short8;
typedef __attribute__((ext_vector_type(8))) unsigned short ushort8;
typedef __attribute__((ext_vector_type(4))) unsigned short ushort4v;
typedef __attribute__((ext_vector_type(4))) float floatx4;

// fp32 -> bf16, round-to-nearest-even
__device__ __forceinline__ unsigned short f2b(float f) {
    union { float f; unsigned int u; } v; v.f = f;
    unsigned int u = v.u;
    unsigned int r = (u + 0x7fffu + ((u >> 16) & 1u)) >> 16;
    return (unsigned short)r;
}
// cheap round-half-up (for P weights; positive values)
__device__ __forceinline__ unsigned short f2b_fast(float f) {
    unsigned int u = __builtin_bit_cast(unsigned int, f);
    return (unsigned short)((u + 0x8000u) >> 16);
}

__device__ __forceinline__ void store_out(unsigned short* p, float v) { *p = f2b(v); }
__device__ __forceinline__ void store_out(float* p, float v) { *p = v; }

// async 16B global -> LDS (dest: wave-uniform base + lane*16)
__device__ __forceinline__ void async16(const unsigned short* g, unsigned short* lds) {
    __builtin_amdgcn_global_load_lds(
        (const __attribute__((address_space(1))) unsigned int*)g,
        (__attribute__((address_space(3))) unsigned int*)lds, 16, 0, 0);
}

// ---------------------------------------------------------------------------
// Prep kernel: blocks 0..2047 cast x fp32->bf16 (8 elems/thread);
// blocks 2048..3071 transpose+cast the two weight matrices (64x64 tiles).
// ---------------------------------------------------------------------------
__global__ __launch_bounds__(256) void prep_kernel(
    const float* __restrict__ x, unsigned short* __restrict__ xb,
    const float* __restrict__ Wqkv, const float* __restrict__ Wproj,
    unsigned short* __restrict__ Wqkv_t, unsigned short* __restrict__ Wproj_t)
{
    __shared__ float tile[64 * 65];
    const int tid = threadIdx.x;
    const int bid = blockIdx.x;

    if (bid < 2048) {                      // ---- cast x ----
        int i = bid * 256 + tid;
        const float4 v0 = *(const float4*)&x[(size_t)i * 8];
        const float4 v1 = *(const float4*)&x[(size_t)i * 8 + 4];
        ushort8 pk;
        pk[0] = f2b(v0.x); pk[1] = f2b(v0.y); pk[2] = f2b(v0.z); pk[3] = f2b(v0.w);
        pk[4] = f2b(v1.x); pk[5] = f2b(v1.y); pk[6] = f2b(v1.z); pk[7] = f2b(v1.w);
        *(ushort8*)&xb[(size_t)i * 8] = pk;
        return;
    }

    // ---- weight transposes ----
    const int xt = bid - 2048;             // 0..1023
    const int cxt = xt & 63;               // col-tile
    const int r0  = (xt >> 6) * 64;        // row-tile base
    const float* src; unsigned short* dst; int Ccols, c0;
    if (cxt < 48) { src = Wqkv;  dst = Wqkv_t;  Ccols = C3; c0 = cxt * 64; }
    else          { src = Wproj; dst = Wproj_t; Ccols = CC; c0 = (cxt - 48) * 64; }
#pragma unroll
    for (int it = 0; it < 4; it++) {
        int idx = it * 256 + tid;
        int row = idx >> 4;
        int c4  = idx & 15;
        float4 v = *(const float4*)&src[(size_t)(r0 + row) * Ccols + c0 + c4 * 4];
        tile[row * 65 + c4 * 4 + 0] = v.x;
        tile[row * 65 + c4 * 4 + 1] = v.y;
        tile[row * 65 + c4 * 4 + 2] = v.z;
        tile[row * 65 + c4 * 4 + 3] = v.w;
    }
    __syncthreads();
#pragma unroll
    for (int it = 0; it < 2; it++) {
        int idx = it * 256 + tid;
        int orow = idx >> 3;
        int o8   = idx & 7;
        ushort8 pk;
#pragma unroll
        for (int j = 0; j < 8; j++) pk[j] = f2b(tile[(o8 * 8 + j) * 65 + orow]);
        *(ushort8*)&dst[(size_t)(c0 + orow) * CC + r0 + o8 * 8] = pk;
    }
}

// ---------------------------------------------------------------------------
// bf16 GEMM, B transposed: 128x128, BK=64, XOR chunk swizzle. (Used for the
// projection GEMM only since R9; QKV uses the 256^2 8-phase kernel below.)
// ---------------------------------------------------------------------------
template <typename OUT_T>
__global__ __launch_bounds__(256) void gemm_bt_kernel(
    const unsigned short* __restrict__ A, const unsigned short* __restrict__ Bm,
    const float* __restrict__ bias, OUT_T* __restrict__ Cmat,
    int M, int N, int K)
{
    __shared__ __align__(16) unsigned short sA[128 * 64];
    __shared__ __align__(16) unsigned short sB[128 * 64];

    const int tid = threadIdx.x;
    const int lane16 = tid & 15, quad = (tid & 63) >> 4;
    const int w = tid >> 6;
    const int wm = w >> 1, wn = w & 1;
    const int m0 = blockIdx.y * 128, n0 = blockIdx.x * 128;
    const int lx = lane16 & 7;

    floatx4 acc[4][4] = {};

    for (int kt = 0; kt < K; kt += 64) {
#pragma unroll
        for (int it = 0; it < 4; it++) {
            int idx = it * 256 + tid;
            int row = idx >> 3;
            int c8m = (idx & 7) ^ (row & 7);
            int wslot = it * 256 + (tid & 192);
            async16(&A[(size_t)(m0 + row) * K + kt + c8m * 8], &sA[wslot * 8]);
            async16(&Bm[(size_t)(n0 + row) * K + kt + c8m * 8], &sB[wslot * 8]);
        }
        __syncthreads();
#pragma unroll
        for (int ks = 0; ks < 64; ks += 32) {
            const int slot = ((ks >> 3) + quad) ^ lx;
            short8 af[4], bf[4];
#pragma unroll
            for (int t = 0; t < 4; t++) {
                af[t] = *(const short8*)&sA[(wm * 64 + t * 16 + lane16) * 64 + slot * 8];
                bf[t] = *(const short8*)&sB[(wn * 64 + t * 16 + lane16) * 64 + slot * 8];
            }
#pragma unroll
            for (int mt = 0; mt < 4; mt++)
#pragma unroll
                for (int nt = 0; nt < 4; nt++)
                    acc[mt][nt] = __builtin_amdgcn_mfma_f32_16x16x32_bf16(
                        af[mt], bf[nt], acc[mt][nt], 0, 0, 0);
        }
        __syncthreads();
    }

#pragma unroll
    for (int mt = 0; mt < 4; mt++) {
#pragma unroll
        for (int nt = 0; nt < 4; nt++) {
            int col = n0 + wn * 64 + nt * 16 + lane16;
            float bv = bias[col];
            int row0 = m0 + wm * 64 + mt * 16 + quad * 4;
#pragma unroll
            for (int r = 0; r < 4; r++)
                store_out(&Cmat[(size_t)(row0 + r) * N + col], acc[mt][nt][r] + bv);
        }
    }
}

// ---------------------------------------------------------------------------
// R9: QKV GEMM, 256x256 tile, 8 waves (2M x 4N), BK=64, counted-vmcnt deep
// pipeline (T3+T4 mechanism). Per K-tile: 4 phases, each {issue 2
// global_load_lds for tile t+1 | ds_read this phase's A-frags | lgkmcnt(0)
// + sched_barrier | setprio(1) 16 MFMA setprio(0)}. Exactly TWO raw
// s_barriers per tile: (1) at phase 0 AFTER s_waitcnt vmcnt(2) - every wave
// certifies its share of tile t's DMA landed before anyone reads it;
// (2) at tile end - all reads of buf pi complete before any wave's next
// stage can overwrite it (issue for tile t+1 targets buf pi^1, whose last
// reader was tile t-1, certified by the previous end-of-tile barrier).
// vmcnt never drains to 0 in the main loop (only 2 loads in flight allowed
// to remain = the ones just issued). LDS 128KB (2 bufs x (A+B) x 256x64),
// 1 block/CU, 2 waves/SIMD. Chunk-XOR swizzle + pre-swizzled source reused
// verbatim from the verified 128^2 kernel. FRAG epilogue: Qf/Kf/Vf in MFMA-
// fragment order (layout as before); Q pre-scaled by log2(e)/8.
// ---------------------------------------------------------------------------
__global__ __launch_bounds__(512, 2) void gemm256_frag_kernel(
    const unsigned short* __restrict__ A, const unsigned short* __restrict__ Bm,
    const float* __restrict__ bias,
    unsigned short* __restrict__ Qf, unsigned short* __restrict__ Kf,
    unsigned short* __restrict__ Vf, float qscale)
{
    // [0 .. 32768): sA[2][256*64]   [32768 .. 65536): sB[2][256*64]
    __shared__ __align__(16) unsigned short sAB[65536];

    const int K = CC;                       // 1024
    const int NT = K / 64;                  // 16 K-tiles
    const int tid = threadIdx.x;
    const int lane16 = tid & 15, quad = (tid & 63) >> 4;
    const int w = tid >> 6;                 // 0..7
    const int wm = w >> 2, wn = w & 3;      // 2M x 4N
    const int m0 = blockIdx.y * 256, n0 = blockIdx.x * 256;
    const int lx = lane16 & 7;
    const int wbase = tid & 0x1C0;          // wave*64

    floatx4 acc[8][4] = {};

    // stage quarter q (rows [64q,64q+64) of A and B) of K-tile tn into bufs
    auto stage = [&](int tn, int q, unsigned short* dA, unsigned short* dB) {
        int idx = q * 512 + tid;
        int row = idx >> 3;
        int cc  = (idx & 7) ^ (row & 7);
        size_t koff = (size_t)tn * 64 + cc * 8;
        int dchunk = (q * 512 + wbase) * 8;
        async16(&A[(size_t)(m0 + row) * K + koff], &dA[dchunk]);
        async16(&Bm[(size_t)(n0 + row) * K + koff], &dB[dchunk]);
    };

    // prologue: stage all of tile 0 (8 loads/thread); t=0 phase 0's
    // vmcnt(2) + barrier certifies it.
    {
        unsigned short* dA = &sAB[0];
        unsigned short* dB = &sAB[32768];
#pragma unroll
        for (int q = 0; q < 4; q++) stage(0, q, dA, dB);
    }

    for (int t = 0; t < NT; ++t) {
        const int pi = t & 1;
        unsigned short* sAc = &sAB[pi * 16384];
        unsigned short* sBc = &sAB[32768 + pi * 16384];
        unsigned short* sAn = &sAB[(pi ^ 1) * 16384];
        unsigned short* sBn = &sAB[32768 + (pi ^ 1) * 16384];
        const bool pre = (t + 1 < NT);

        // ---- phase 0 ----
        if (pre) {
            stage(t + 1, 0, sAn, sBn);
            asm volatile("s_waitcnt vmcnt(2)" ::: "memory");
        } else {
            asm volatile("s_waitcnt vmcnt(0)" ::: "memory");
        }
        __builtin_amdgcn_s_barrier();       // all waves: tile t landed

        short8 bf[4][2];
#pragma unroll
        for (int nt = 0; nt < 4; nt++)
#pragma unroll
            for (int ks = 0; ks < 2; ks++) {
                int r = wn * 64 + nt * 16 + lane16;
                int slot = (ks * 4 + quad) ^ lx;
                bf[nt][ks] = *(const short8*)&sBc[r * 64 + slot * 8];
            }
        {
            short8 af[2][2];
#pragma unroll
            for (int m2 = 0; m2 < 2; m2++)
#pragma unroll
                for (int ks = 0; ks < 2; ks++) {
                    int r = wm * 128 + m2 * 16 + lane16;
                    int slot = (ks * 4 + quad) ^ lx;
                    af[m2][ks] = *(const short8*)&sAc[r * 64 + slot * 8];
                }
            asm volatile("s_waitcnt lgkmcnt(0)" ::: "memory");
            __builtin_amdgcn_sched_barrier(0);
            __builtin_amdgcn_s_setprio(1);
#pragma unroll
            for (int m2 = 0; m2 < 2; m2++)
#pragma unroll
                for (int nt = 0; nt < 4; nt++)
#pragma unroll
                    for (int ks = 0; ks < 2; ks++)
                        acc[m2][nt] = __builtin_amdgcn_mfma_f32_16x16x32_bf16(
                            af[m2][ks], bf[nt][ks], acc[m2][nt], 0, 0, 0);
            __builtin_amdgcn_s_setprio(0);
        }

        // ---- phases 1..3 ----
#pragma unroll
        for (int q = 1; q < 4; q++) {
            if (pre) stage(t + 1, q, sAn, sBn);
            short8 af[2][2];
#pragma unroll
            for (int m2 = 0; m2 < 2; m2++)
#pragma unroll
                for (int ks = 0; ks < 2; ks++) {
                    int r = wm * 128 + (2 * q + m2) * 16 + lane16;
                    int slot = (ks * 4 + quad) ^ lx;
                    af[m2][ks] = *(const short8*)&sAc[r * 64 + slot * 8];
                }
            asm volatile("s_waitcnt lgkmcnt(0)" ::: "memory");
            __builtin_amdgcn_sched_barrier(0);
            __builtin_amdgcn_s_setprio(1);
#pragma unroll
            for (int m2 = 0; m2 < 2; m2++)
#pragma unroll
                for (int nt = 0; nt < 4; nt++)
#pragma unroll
                    for (int ks = 0; ks < 2; ks++)
                        acc[2 * q + m2][nt] = __builtin_amdgcn_mfma_f32_16x16x32_bf16(
                            af[m2][ks], bf[nt][ks], acc[2 * q + m2][nt], 0, 0, 0);
            __builtin_amdgcn_s_setprio(0);
        }

        __builtin_amdgcn_s_barrier();       // all reads of buf pi done
    }

    // ---- FRAG epilogue: Qf/Kf/Vf in MFMA-fragment order ----
#pragma unroll
    for (int mt = 0; mt < 8; mt++) {
#pragma unroll
        for (int nt = 0; nt < 4; nt++) {
            int col = n0 + wn * 64 + nt * 16 + lane16;
            float bv = bias[col];
            int row0 = m0 + wm * 128 + mt * 16 + quad * 4;
            const int breg = row0 >> 11;            // batch
            const int tok0 = row0 & (TT - 1);       // token (4-aligned)
            if (col < CC) {                          // ---- Q (scaled) ----
                int h = col >> 6, d = col & 63;
                int bh = breg * HH + h;
                size_t base = ((size_t)(bh * 128 + (tok0 >> 4)) * 2 + (d >> 5)) * 512
                            + ((d >> 3) & 3) * 128 + (tok0 & 15) * 8 + (d & 7);
#pragma unroll
                for (int r = 0; r < 4; r++)
                    Qf[base + r * 8] = f2b((acc[mt][nt][r] + bv) * qscale);
            } else if (col < 2 * CC) {               // ---- K ----
                int c = col - CC;
                int h = c >> 6, d = c & 63;
                int bh = breg * HH + h;
                size_t base = ((size_t)(bh * 128 + (tok0 >> 4)) * 2 + (d >> 5)) * 512
                            + ((d >> 3) & 3) * 128 + (tok0 & 15) * 8 + (d & 7);
#pragma unroll
                for (int r = 0; r < 4; r++)
                    Kf[base + r * 8] = f2b(acc[mt][nt][r] + bv);
            } else {                                 // ---- V ----
                int c = col - 2 * CC;
                int h = c >> 6, d = c & 63;
                int bh = breg * HH + h;
                size_t base = ((size_t)(bh * 64 + (tok0 >> 5)) * 4 + (d >> 4)) * 512
                            + (((tok0 >> 2) & 3) * 16 + (d & 15)) * 8
                            + ((tok0 >> 4) & 1) * 4;
                ushort4v pk;
#pragma unroll
                for (int r = 0; r < 4; r++) pk[r] = f2b(acc[mt][nt][r] + bv);
                *(ushort4v*)&Vf[base] = pk;
            }
        }
    }
}

// ---------------------------------------------------------------------------
// Flash attention (R8, verified): 4-wave block / 64-row q-tile, K/V staged
// per tile into LDS in fragment-chunk order via global_load_lds; lane-linear
// ds_read_b128 (zero bank conflicts); double-buffered, one barrier/tile.
// Swapped QK^T + in-register P. Grid (32 bh, 32 y), balanced p-map.
// ---------------------------------------------------------------------------
__global__ __launch_bounds__(256) void attn_mfma_kernel(
    const unsigned short* __restrict__ Qf, const unsigned short* __restrict__ Kf,
    const unsigned short* __restrict__ Vf, unsigned short* __restrict__ att)
{
    __shared__ __align__(16) unsigned short Ks[2][8 * 512];   // 8KB per buf
    __shared__ __align__(16) unsigned short Vs[2][8 * 512];   // 8KB per buf

    const int tid = threadIdx.x;
    const int l = tid & 63;
    const int w = tid >> 6;
    const int lane16 = l & 15, quad = l >> 4;
    const int bh = blockIdx.x;                    // same head -> same XCD
    const int b = bh >> 4, h = bh & 15;

    // balanced q-tile assignment (every CU's 4 blocks sum to 66 tile-units)
    const int y = blockIdx.y;                     // 0..31
    const int gcu = y & 7, s = y >> 3;
    const int p = 8 * s + ((s & 1) ? (7 - gcu) : gcu);
    const int q0 = p * 64;
    const int qw = q0 + w * 16;                   // this wave's 16 q-rows

    const unsigned short* Qb  = Qf + (size_t)bh * 131072 + l * 8;
    const unsigned short* KbT = Kf + (size_t)bh * 131072;
    const unsigned short* VbT = Vf + (size_t)bh * 131072;

    // Q fragments (B-operand layout: n=lane16=q, k=quad*8+j=d)
    short8 qf0 = *(const short8*)&Qb[(size_t)((qw >> 4) * 2 + 0) * 512];
    short8 qf1 = *(const short8*)&Qb[(size_t)((qw >> 4) * 2 + 1) * 512];

    floatx4 O[4] = {};                            // [dt]
    float ps = 0.f;                               // row-sum partial
    const int ntiles = p + 1;
    const int qrow = qw + lane16;                 // this lane's global q row

    // stage tile tt into LDS buffer buf: 16 chunks (K:0..7, V:8..15) split
    // 4 per wave; async16 dest = wave-uniform chunk base (+HW lane*16)
    auto stage = [&](int tt, int buf) {
#pragma unroll
        for (int s4 = 0; s4 < 4; s4++) {
            int c = s4 * 4 + w;
            if (c < 8)
                async16(&KbT[((size_t)tt * 8 + c) * 512 + l * 8], &Ks[buf][c * 512]);
            else
                async16(&VbT[((size_t)tt * 8 + (c - 8)) * 512 + l * 8], &Vs[buf][(c - 8) * 512]);
        }
    };

    stage(0, 0);
    __syncthreads();                              // drain stage of tile 0

    int cur = 0;
    for (int t = 0; t < ntiles; ++t) {
        if (t + 1 < ntiles) stage(t + 1, cur ^ 1);   // async into other buffer

        // ---- K fragments from LDS (lane-linear b128, conflict-free) ----
        short8 kf[8];
#pragma unroll
        for (int i = 0; i < 8; i++)
            kf[i] = *(const short8*)&Ks[cur][i * 512 + l * 8];

        // ---- S^T = K Q^T ; p = exp2(s); pack P as PV A-frag words ----
        const bool last = (t == ntiles - 1);
        short8 pa[2];                             // [kc]
#pragma unroll
        for (int nt = 0; nt < 4; nt++) {
            floatx4 s4v = {};
            s4v = __builtin_amdgcn_mfma_f32_16x16x32_bf16(kf[nt * 2 + 0], qf0, s4v, 0, 0, 0);
            s4v = __builtin_amdgcn_mfma_f32_16x16x32_bf16(kf[nt * 2 + 1], qf1, s4v, 0, 0, 0);
#pragma unroll
            for (int r = 0; r < 4; r++) {
                float v = s4v[r];
                if (last) {                       // diag tile: causal mask
                    int key = t * 64 + nt * 16 + quad * 4 + r;
                    if (key > qrow) v = -1e30f;
                }
                float pe = __builtin_amdgcn_exp2f(v);
                ps += pe;
                pa[nt >> 1][(nt & 1) * 4 + r] = (short)f2b_fast(pe);
            }
        }

        // ---- O += P V (V fragments from LDS, lane-linear b128) ----
#pragma unroll
        for (int kc = 0; kc < 2; kc++) {
            short8 vfr[4];
#pragma unroll
            for (int i = 0; i < 4; i++)
                vfr[i] = *(const short8*)&Vs[cur][(kc * 4 + i) * 512 + l * 8];
#pragma unroll
            for (int dt = 0; dt < 4; dt++)
                O[dt] = __builtin_amdgcn_mfma_f32_16x16x32_bf16(
                    pa[kc], vfr[dt], O[dt], 0, 0, 0);
        }

        __syncthreads();   // LDS reads done + next-tile stage drained (vmcnt)
        cur ^= 1;
    }

    // combine the 4 quads' row-sum partials (same lane16 = same q-row)
    ps += __shfl_xor(ps, 16, 64);
    ps += __shfl_xor(ps, 32, 64);

    unsigned short* ob = att + ((size_t)(b * TT) + qw) * CC + h * DD;
#pragma unroll
    for (int r = 0; r < 4; r++) {
        float rl = 1.0f / __shfl(ps, quad * 4 + r, 16);
        int q = quad * 4 + r;
#pragma unroll
        for (int dt = 0; dt < 4; dt++)
            ob[(size_t)q * CC + dt * 16 + lane16] = f2b(O[dt][r] * rl);
    }
}

// ---------------------------------------------------------------------------
extern "C" void kernel_launch(void* const* d_in, const int* in_sizes, int n_in,
                              void* d_out, int out_size, void* d_ws, size_t ws_size,
                              hipStream_t stream) {
    const float* x     = (const float*)d_in[0];
    const float* Wqkv  = (const float*)d_in[1];
    const float* bqkv  = (const float*)d_in[2];
    const float* Wproj = (const float*)d_in[3];
    const float* bproj = (const float*)d_in[4];
    float* out = (float*)d_out;

    const size_t FRAG_ELEMS = (size_t)128 * 2 * 512;             // 131072 per bh
    unsigned short* xb      = (unsigned short*)d_ws;             // [4096][1024]
    unsigned short* Qf      = xb + (size_t)BT * CC;              // [32][131072]
    unsigned short* Kf      = Qf + (size_t)BB * HH * FRAG_ELEMS;
    unsigned short* Vf      = Kf + (size_t)BB * HH * FRAG_ELEMS;
    unsigned short* Wqkv_t  = Vf + (size_t)BB * HH * FRAG_ELEMS; // [3072][1024]
    unsigned short* Wproj_t = Wqkv_t + (size_t)C3 * CC;          // [1024][1024]
    unsigned short* att_b   = Wproj_t + (size_t)CC * CC;         // [4096][1024]

    // 1) input cast + weight transposes (one launch)
    prep_kernel<<<3072, 256, 0, stream>>>(x, xb, Wqkv, Wproj, Wqkv_t, Wproj_t);

    // 2) QKV GEMM (256^2 8-wave, counted-vmcnt pipeline) -> Qf/Kf/Vf
    {
        dim3 grid(C3 / 256, BT / 256);   // 12 x 16 = 192 blocks
        gemm256_frag_kernel<<<grid, 512, 0, stream>>>(
            xb, Wqkv_t, bqkv, Qf, Kf, Vf, 0.125f * 1.44269504f);
    }
    // 3) flash attention (4-wave blocks, async fragment-chunk LDS staging)
    {
        dim3 grid(BB * HH, 32);
        attn_mfma_kernel<<<grid, 256, 0, stream>>>(Qf, Kf, Vf, att_b);
    }
    // 4) projection GEMM -> fp32 out
    {
        dim3 grid(CC / 128, BT / 128);
        gemm_bt_kernel<float><<<grid, 256, 0, stream>>>(
            att_b, Wproj_t, bproj, out, BT, CC, CC);
    }
}

// Round 11
// 168.189 us; speedup vs baseline: 1.0353x; 1.0353x over previous
//
#include <hip/hip_runtime.h>
#include <hip/hip_bf16.h>
#include <math.h>

#define BB 2
#define TT 2048
#define CC 1024
#define HH 16
#define DD 64
#define C3 3072
#define BT 4096

typedef __attribute__((ext_vector_type(8))) short short8;
typedef __attribute__((ext_vector_type(8))) unsigned short ushort8;
typedef __attribute__((ext_vector_type(4))) unsigned short ushort4v;
typedef __attribute__((ext_vector_type(4))) float floatx4;

// fp32 -> bf16, round-to-nearest-even
__device__ __forceinline__ unsigned short f2b(float f) {
    union { float f; unsigned int u; } v; v.f = f;
    unsigned int u = v.u;
    unsigned int r = (u + 0x7fffu + ((u >> 16) & 1u)) >> 16;
    return (unsigned short)r;
}
// cheap round-half-up (for P weights; positive values)
__device__ __forceinline__ unsigned short f2b_fast(float f) {
    unsigned int u = __builtin_bit_cast(unsigned int, f);
    return (unsigned short)((u + 0x8000u) >> 16);
}

__device__ __forceinline__ void store_out(unsigned short* p, float v) { *p = f2b(v); }
__device__ __forceinline__ void store_out(float* p, float v) { *p = v; }

// async 16B global -> LDS (dest: wave-uniform base + lane*16)
__device__ __forceinline__ void async16(const unsigned short* g, unsigned short* lds) {
    __builtin_amdgcn_global_load_lds(
        (const __attribute__((address_space(1))) unsigned int*)g,
        (__attribute__((address_space(3))) unsigned int*)lds, 16, 0, 0);
}

// ---------------------------------------------------------------------------
// Prep kernel: blocks 0..2047 cast x fp32->bf16 (8 elems/thread);
// blocks 2048..3071 transpose+cast the two weight matrices (64x64 tiles).
// ---------------------------------------------------------------------------
__global__ __launch_bounds__(256) void prep_kernel(
    const float* __restrict__ x, unsigned short* __restrict__ xb,
    const float* __restrict__ Wqkv, const float* __restrict__ Wproj,
    unsigned short* __restrict__ Wqkv_t, unsigned short* __restrict__ Wproj_t)
{
    __shared__ float tile[64 * 65];
    const int tid = threadIdx.x;
    const int bid = blockIdx.x;

    if (bid < 2048) {                      // ---- cast x ----
        int i = bid * 256 + tid;
        const float4 v0 = *(const float4*)&x[(size_t)i * 8];
        const float4 v1 = *(const float4*)&x[(size_t)i * 8 + 4];
        ushort8 pk;
        pk[0] = f2b(v0.x); pk[1] = f2b(v0.y); pk[2] = f2b(v0.z); pk[3] = f2b(v0.w);
        pk[4] = f2b(v1.x); pk[5] = f2b(v1.y); pk[6] = f2b(v1.z); pk[7] = f2b(v1.w);
        *(ushort8*)&xb[(size_t)i * 8] = pk;
        return;
    }

    // ---- weight transposes ----
    const int xt = bid - 2048;             // 0..1023
    const int cxt = xt & 63;               // col-tile
    const int r0  = (xt >> 6) * 64;        // row-tile base
    const float* src; unsigned short* dst; int Ccols, c0;
    if (cxt < 48) { src = Wqkv;  dst = Wqkv_t;  Ccols = C3; c0 = cxt * 64; }
    else          { src = Wproj; dst = Wproj_t; Ccols = CC; c0 = (cxt - 48) * 64; }
#pragma unroll
    for (int it = 0; it < 4; it++) {
        int idx = it * 256 + tid;
        int row = idx >> 4;
        int c4  = idx & 15;
        float4 v = *(const float4*)&src[(size_t)(r0 + row) * Ccols + c0 + c4 * 4];
        tile[row * 65 + c4 * 4 + 0] = v.x;
        tile[row * 65 + c4 * 4 + 1] = v.y;
        tile[row * 65 + c4 * 4 + 2] = v.z;
        tile[row * 65 + c4 * 4 + 3] = v.w;
    }
    __syncthreads();
#pragma unroll
    for (int it = 0; it < 2; it++) {
        int idx = it * 256 + tid;
        int orow = idx >> 3;
        int o8   = idx & 7;
        ushort8 pk;
#pragma unroll
        for (int j = 0; j < 8; j++) pk[j] = f2b(tile[(o8 * 8 + j) * 65 + orow]);
        *(ushort8*)&dst[(size_t)(c0 + orow) * CC + r0 + o8 * 8] = pk;
    }
}

// ---------------------------------------------------------------------------
// Projection GEMM, R10: 128x128 tile, BK=64, chunk-XOR swizzle (verified
// dataflow), now with EIGHT waves (4M x 2N, acc[2][4]) instead of four.
// Old grid (8,32)=256 blocks x 4 waves = 1 wave/SIMD (latency exposed);
// same grid x 8 waves = 2 waves/SIMD. Staging identical swizzle, collapsed
// to 2 iterations of 512 threads (wslot = it*512 + wave*64).
// ---------------------------------------------------------------------------
template <typename OUT_T>
__global__ __launch_bounds__(512) void gemm_bt_kernel(
    const unsigned short* __restrict__ A, const unsigned short* __restrict__ Bm,
    const float* __restrict__ bias, OUT_T* __restrict__ Cmat,
    int M, int N, int K)
{
    __shared__ __align__(16) unsigned short sA[128 * 64];
    __shared__ __align__(16) unsigned short sB[128 * 64];

    const int tid = threadIdx.x;
    const int lane16 = tid & 15, quad = (tid & 63) >> 4;
    const int w = tid >> 6;                 // 0..7
    const int wm = w >> 1, wn = w & 1;      // 4M x 2N
    const int m0 = blockIdx.y * 128, n0 = blockIdx.x * 128;
    const int lx = lane16 & 7;

    floatx4 acc[2][4] = {};

    for (int kt = 0; kt < K; kt += 64) {
#pragma unroll
        for (int it = 0; it < 2; it++) {
            int idx = it * 512 + tid;
            int row = idx >> 3;
            int c8m = (idx & 7) ^ (row & 7);
            int wslot = it * 512 + (tid & 448);
            async16(&A[(size_t)(m0 + row) * K + kt + c8m * 8], &sA[wslot * 8]);
            async16(&Bm[(size_t)(n0 + row) * K + kt + c8m * 8], &sB[wslot * 8]);
        }
        __syncthreads();
#pragma unroll
        for (int ks = 0; ks < 2; ks++) {
            const int slot = (ks * 4 + quad) ^ lx;
            short8 af[2], bf[4];
#pragma unroll
            for (int t = 0; t < 2; t++)
                af[t] = *(const short8*)&sA[(wm * 32 + t * 16 + lane16) * 64 + slot * 8];
#pragma unroll
            for (int t = 0; t < 4; t++)
                bf[t] = *(const short8*)&sB[(wn * 64 + t * 16 + lane16) * 64 + slot * 8];
#pragma unroll
            for (int mt = 0; mt < 2; mt++)
#pragma unroll
                for (int nt = 0; nt < 4; nt++)
                    acc[mt][nt] = __builtin_amdgcn_mfma_f32_16x16x32_bf16(
                        af[mt], bf[nt], acc[mt][nt], 0, 0, 0);
        }
        __syncthreads();
    }

#pragma unroll
    for (int mt = 0; mt < 2; mt++) {
#pragma unroll
        for (int nt = 0; nt < 4; nt++) {
            int col = n0 + wn * 64 + nt * 16 + lane16;
            float bv = bias[col];
            int row0 = m0 + wm * 32 + mt * 16 + quad * 4;
#pragma unroll
            for (int r = 0; r < 4; r++)
                store_out(&Cmat[(size_t)(row0 + r) * N + col], acc[mt][nt][r] + bv);
        }
    }
}

// ---------------------------------------------------------------------------
// QKV GEMM (R9, kept): 256x256 tile, 8 waves (2M x 4N), BK=64, 1-tile-deep
// async prefetch spread over 4 phases, two raw s_barriers per tile,
// vmcnt never drained to 0 in the main loop. FRAG epilogue: Qf/Kf/Vf in
// MFMA-fragment order; Q pre-scaled by log2(e)/8.
// ---------------------------------------------------------------------------
__global__ __launch_bounds__(512, 2) void gemm256_frag_kernel(
    const unsigned short* __restrict__ A, const unsigned short* __restrict__ Bm,
    const float* __restrict__ bias,
    unsigned short* __restrict__ Qf, unsigned short* __restrict__ Kf,
    unsigned short* __restrict__ Vf, float qscale)
{
    // [0 .. 32768): sA[2][256*64]   [32768 .. 65536): sB[2][256*64]
    __shared__ __align__(16) unsigned short sAB[65536];

    const int K = CC;                       // 1024
    const int NT = K / 64;                  // 16 K-tiles
    const int tid = threadIdx.x;
    const int lane16 = tid & 15, quad = (tid & 63) >> 4;
    const int w = tid >> 6;                 // 0..7
    const int wm = w >> 2, wn = w & 3;      // 2M x 4N
    const int m0 = blockIdx.y * 256, n0 = blockIdx.x * 256;
    const int lx = lane16 & 7;
    const int wbase = tid & 0x1C0;          // wave*64

    floatx4 acc[8][4] = {};

    // stage quarter q (rows [64q,64q+64) of A and B) of K-tile tn into bufs
    auto stage = [&](int tn, int q, unsigned short* dA, unsigned short* dB) {
        int idx = q * 512 + tid;
        int row = idx >> 3;
        int cc  = (idx & 7) ^ (row & 7);
        size_t koff = (size_t)tn * 64 + cc * 8;
        int dchunk = (q * 512 + wbase) * 8;
        async16(&A[(size_t)(m0 + row) * K + koff], &dA[dchunk]);
        async16(&Bm[(size_t)(n0 + row) * K + koff], &dB[dchunk]);
    };

    // prologue: stage all of tile 0 (8 loads/thread); t=0 phase 0's
    // vmcnt(2) + barrier certifies it.
    {
        unsigned short* dA = &sAB[0];
        unsigned short* dB = &sAB[32768];
#pragma unroll
        for (int q = 0; q < 4; q++) stage(0, q, dA, dB);
    }

    for (int t = 0; t < NT; ++t) {
        const int pi = t & 1;
        unsigned short* sAc = &sAB[pi * 16384];
        unsigned short* sBc = &sAB[32768 + pi * 16384];
        unsigned short* sAn = &sAB[(pi ^ 1) * 16384];
        unsigned short* sBn = &sAB[32768 + (pi ^ 1) * 16384];
        const bool pre = (t + 1 < NT);

        // ---- phase 0 ----
        if (pre) {
            stage(t + 1, 0, sAn, sBn);
            asm volatile("s_waitcnt vmcnt(2)" ::: "memory");
        } else {
            asm volatile("s_waitcnt vmcnt(0)" ::: "memory");
        }
        __builtin_amdgcn_s_barrier();       // all waves: tile t landed

        short8 bf[4][2];
#pragma unroll
        for (int nt = 0; nt < 4; nt++)
#pragma unroll
            for (int ks = 0; ks < 2; ks++) {
                int r = wn * 64 + nt * 16 + lane16;
                int slot = (ks * 4 + quad) ^ lx;
                bf[nt][ks] = *(const short8*)&sBc[r * 64 + slot * 8];
            }
        {
            short8 af[2][2];
#pragma unroll
            for (int m2 = 0; m2 < 2; m2++)
#pragma unroll
                for (int ks = 0; ks < 2; ks++) {
                    int r = wm * 128 + m2 * 16 + lane16;
                    int slot = (ks * 4 + quad) ^ lx;
                    af[m2][ks] = *(const short8*)&sAc[r * 64 + slot * 8];
                }
            asm volatile("s_waitcnt lgkmcnt(0)" ::: "memory");
            __builtin_amdgcn_sched_barrier(0);
            __builtin_amdgcn_s_setprio(1);
#pragma unroll
            for (int m2 = 0; m2 < 2; m2++)
#pragma unroll
                for (int nt = 0; nt < 4; nt++)
#pragma unroll
                    for (int ks = 0; ks < 2; ks++)
                        acc[m2][nt] = __builtin_amdgcn_mfma_f32_16x16x32_bf16(
                            af[m2][ks], bf[nt][ks], acc[m2][nt], 0, 0, 0);
            __builtin_amdgcn_s_setprio(0);
        }

        // ---- phases 1..3 ----
#pragma unroll
        for (int q = 1; q < 4; q++) {
            if (pre) stage(t + 1, q, sAn, sBn);
            short8 af[2][2];
#pragma unroll
            for (int m2 = 0; m2 < 2; m2++)
#pragma unroll
                for (int ks = 0; ks < 2; ks++) {
                    int r = wm * 128 + (2 * q + m2) * 16 + lane16;
                    int slot = (ks * 4 + quad) ^ lx;
                    af[m2][ks] = *(const short8*)&sAc[r * 64 + slot * 8];
                }
            asm volatile("s_waitcnt lgkmcnt(0)" ::: "memory");
            __builtin_amdgcn_sched_barrier(0);
            __builtin_amdgcn_s_setprio(1);
#pragma unroll
            for (int m2 = 0; m2 < 2; m2++)
#pragma unroll
                for (int nt = 0; nt < 4; nt++)
#pragma unroll
                    for (int ks = 0; ks < 2; ks++)
                        acc[2 * q + m2][nt] = __builtin_amdgcn_mfma_f32_16x16x32_bf16(
                            af[m2][ks], bf[nt][ks], acc[2 * q + m2][nt], 0, 0, 0);
            __builtin_amdgcn_s_setprio(0);
        }

        __builtin_amdgcn_s_barrier();       // all reads of buf pi done
    }

    // ---- FRAG epilogue: Qf/Kf/Vf in MFMA-fragment order ----
#pragma unroll
    for (int mt = 0; mt < 8; mt++) {
#pragma unroll
        for (int nt = 0; nt < 4; nt++) {
            int col = n0 + wn * 64 + nt * 16 + lane16;
            float bv = bias[col];
            int row0 = m0 + wm * 128 + mt * 16 + quad * 4;
            const int breg = row0 >> 11;            // batch
            const int tok0 = row0 & (TT - 1);       // token (4-aligned)
            if (col < CC) {                          // ---- Q (scaled) ----
                int h = col >> 6, d = col & 63;
                int bh = breg * HH + h;
                size_t base = ((size_t)(bh * 128 + (tok0 >> 4)) * 2 + (d >> 5)) * 512
                            + ((d >> 3) & 3) * 128 + (tok0 & 15) * 8 + (d & 7);
#pragma unroll
                for (int r = 0; r < 4; r++)
                    Qf[base + r * 8] = f2b((acc[mt][nt][r] + bv) * qscale);
            } else if (col < 2 * CC) {               // ---- K ----
                int c = col - CC;
                int h = c >> 6, d = c & 63;
                int bh = breg * HH + h;
                size_t base = ((size_t)(bh * 128 + (tok0 >> 4)) * 2 + (d >> 5)) * 512
                            + ((d >> 3) & 3) * 128 + (tok0 & 15) * 8 + (d & 7);
#pragma unroll
                for (int r = 0; r < 4; r++)
                    Kf[base + r * 8] = f2b(acc[mt][nt][r] + bv);
            } else {                                 // ---- V ----
                int c = col - 2 * CC;
                int h = c >> 6, d = c & 63;
                int bh = breg * HH + h;
                size_t base = ((size_t)(bh * 64 + (tok0 >> 5)) * 4 + (d >> 4)) * 512
                            + (((tok0 >> 2) & 3) * 16 + (d & 15)) * 8
                            + ((tok0 >> 4) & 1) * 4;
                ushort4v pk;
#pragma unroll
                for (int r = 0; r < 4; r++) pk[r] = f2b(acc[mt][nt][r] + bv);
                *(ushort4v*)&Vf[base] = pk;
            }
        }
    }
}

// ---------------------------------------------------------------------------
// Flash attention (R8, verified): 4-wave block / 64-row q-tile, K/V staged
// per tile into LDS in fragment-chunk order via global_load_lds; lane-linear
// ds_read_b128 (zero bank conflicts); double-buffered, one barrier/tile.
// Swapped QK^T + in-register P. Grid (32 bh, 32 y), balanced p-map.
// ---------------------------------------------------------------------------
__global__ __launch_bounds__(256) void attn_mfma_kernel(
    const unsigned short* __restrict__ Qf, const unsigned short* __restrict__ Kf,
    const unsigned short* __restrict__ Vf, unsigned short* __restrict__ att)
{
    __shared__ __align__(16) unsigned short Ks[2][8 * 512];   // 8KB per buf
    __shared__ __align__(16) unsigned short Vs[2][8 * 512];   // 8KB per buf

    const int tid = threadIdx.x;
    const int l = tid & 63;
    const int w = tid >> 6;
    const int lane16 = l & 15, quad = l >> 4;
    const int bh = blockIdx.x;                    // same head -> same XCD
    const int b = bh >> 4, h = bh & 15;

    // balanced q-tile assignment (every CU's 4 blocks sum to 66 tile-units)
    const int y = blockIdx.y;                     // 0..31
    const int gcu = y & 7, s = y >> 3;
    const int p = 8 * s + ((s & 1) ? (7 - gcu) : gcu);
    const int q0 = p * 64;
    const int qw = q0 + w * 16;                   // this wave's 16 q-rows

    const unsigned short* Qb  = Qf + (size_t)bh * 131072 + l * 8;
    const unsigned short* KbT = Kf + (size_t)bh * 131072;
    const unsigned short* VbT = Vf + (size_t)bh * 131072;

    // Q fragments (B-operand layout: n=lane16=q, k=quad*8+j=d)
    short8 qf0 = *(const short8*)&Qb[(size_t)((qw >> 4) * 2 + 0) * 512];
    short8 qf1 = *(const short8*)&Qb[(size_t)((qw >> 4) * 2 + 1) * 512];

    floatx4 O[4] = {};                            // [dt]
    float ps = 0.f;                               // row-sum partial
    const int ntiles = p + 1;
    const int qrow = qw + lane16;                 // this lane's global q row

    // stage tile tt into LDS buffer buf: 16 chunks (K:0..7, V:8..15) split
    // 4 per wave; async16 dest = wave-uniform chunk base (+HW lane*16)
    auto stage = [&](int tt, int buf) {
#pragma unroll
        for (int s4 = 0; s4 < 4; s4++) {
            int c = s4 * 4 + w;
            if (c < 8)
                async16(&KbT[((size_t)tt * 8 + c) * 512 + l * 8], &Ks[buf][c * 512]);
            else
                async16(&VbT[((size_t)tt * 8 + (c - 8)) * 512 + l * 8], &Vs[buf][(c - 8) * 512]);
        }
    };

    stage(0, 0);
    __syncthreads();                              // drain stage of tile 0

    int cur = 0;
    for (int t = 0; t < ntiles; ++t) {
        if (t + 1 < ntiles) stage(t + 1, cur ^ 1);   // async into other buffer

        // ---- K fragments from LDS (lane-linear b128, conflict-free) ----
        short8 kf[8];
#pragma unroll
        for (int i = 0; i < 8; i++)
            kf[i] = *(const short8*)&Ks[cur][i * 512 + l * 8];

        // ---- S^T = K Q^T ; p = exp2(s); pack P as PV A-frag words ----
        const bool last = (t == ntiles - 1);
        short8 pa[2];                             // [kc]
#pragma unroll
        for (int nt = 0; nt < 4; nt++) {
            floatx4 s4v = {};
            s4v = __builtin_amdgcn_mfma_f32_16x16x32_bf16(kf[nt * 2 + 0], qf0, s4v, 0, 0, 0);
            s4v = __builtin_amdgcn_mfma_f32_16x16x32_bf16(kf[nt * 2 + 1], qf1, s4v, 0, 0, 0);
#pragma unroll
            for (int r = 0; r < 4; r++) {
                float v = s4v[r];
                if (last) {                       // diag tile: causal mask
                    int key = t * 64 + nt * 16 + quad * 4 + r;
                    if (key > qrow) v = -1e30f;
                }
                float pe = __builtin_amdgcn_exp2f(v);
                ps += pe;
                pa[nt >> 1][(nt & 1) * 4 + r] = (short)f2b_fast(pe);
            }
        }

        // ---- O += P V (V fragments from LDS, lane-linear b128) ----
#pragma unroll
        for (int kc = 0; kc < 2; kc++) {
            short8 vfr[4];
#pragma unroll
            for (int i = 0; i < 4; i++)
                vfr[i] = *(const short8*)&Vs[cur][(kc * 4 + i) * 512 + l * 8];
#pragma unroll
            for (int dt = 0; dt < 4; dt++)
                O[dt] = __builtin_amdgcn_mfma_f32_16x16x32_bf16(
                    pa[kc], vfr[dt], O[dt], 0, 0, 0);
        }

        __syncthreads();   // LDS reads done + next-tile stage drained (vmcnt)
        cur ^= 1;
    }

    // combine the 4 quads' row-sum partials (same lane16 = same q-row)
    ps += __shfl_xor(ps, 16, 64);
    ps += __shfl_xor(ps, 32, 64);

    unsigned short* ob = att + ((size_t)(b * TT) + qw) * CC + h * DD;
#pragma unroll
    for (int r = 0; r < 4; r++) {
        float rl = 1.0f / __shfl(ps, quad * 4 + r, 16);
        int q = quad * 4 + r;
#pragma unroll
        for (int dt = 0; dt < 4; dt++)
            ob[(size_t)q * CC + dt * 16 + lane16] = f2b(O[dt][r] * rl);
    }
}

// ---------------------------------------------------------------------------
extern "C" void kernel_launch(void* const* d_in, const int* in_sizes, int n_in,
                              void* d_out, int out_size, void* d_ws, size_t ws_size,
                              hipStream_t stream) {
    const float* x     = (const float*)d_in[0];
    const float* Wqkv  = (const float*)d_in[1];
    const float* bqkv  = (const float*)d_in[2];
    const float* Wproj = (const float*)d_in[3];
    const float* bproj = (const float*)d_in[4];
    float* out = (float*)d_out;

    const size_t FRAG_ELEMS = (size_t)128 * 2 * 512;             // 131072 per bh
    unsigned short* xb      = (unsigned short*)d_ws;             // [4096][1024]
    unsigned short* Qf      = xb + (size_t)BT * CC;              // [32][131072]
    unsigned short* Kf      = Qf + (size_t)BB * HH * FRAG_ELEMS;
    unsigned short* Vf      = Kf + (size_t)BB * HH * FRAG_ELEMS;
    unsigned short* Wqkv_t  = Vf + (size_t)BB * HH * FRAG_ELEMS; // [3072][1024]
    unsigned short* Wproj_t = Wqkv_t + (size_t)C3 * CC;          // [1024][1024]
    unsigned short* att_b   = Wproj_t + (size_t)CC * CC;         // [4096][1024]

    // 1) input cast + weight transposes (one launch)
    prep_kernel<<<3072, 256, 0, stream>>>(x, xb, Wqkv, Wproj, Wqkv_t, Wproj_t);

    // 2) QKV GEMM (256^2 8-wave, async-prefetch pipeline) -> Qf/Kf/Vf
    {
        dim3 grid(C3 / 256, BT / 256);   // 12 x 16 = 192 blocks
        gemm256_frag_kernel<<<grid, 512, 0, stream>>>(
            xb, Wqkv_t, bqkv, Qf, Kf, Vf, 0.125f * 1.44269504f);
    }
    // 3) flash attention (4-wave blocks, async fragment-chunk LDS staging)
    {
        dim3 grid(BB * HH, 32);
        attn_mfma_kernel<<<grid, 256, 0, stream>>>(Qf, Kf, Vf, att_b);
    }
    // 4) projection GEMM (8-wave 128^2, 2 waves/SIMD) -> fp32 out
    {
        dim3 grid(CC / 128, BT / 128);
        gemm_bt_kernel<float><<<grid, 512, 0, stream>>>(
            att_b, Wproj_t, bproj, out, BT, CC, CC);
    }
}

// Round 12
// 167.598 us; speedup vs baseline: 1.0389x; 1.0035x over previous
//
#include <hip/hip_runtime.h>
#include <hip/hip_bf16.h>
#include <math.h>

#define BB 2
#define TT 2048
#define CC 1024
#define HH 16
#define DD 64
#define C3 3072
#define BT 4096

typedef __attribute__((ext_vector_type(8))) short short8;
typedef __attribute__((ext_vector_type(8))) unsigned short ushort8;
typedef __attribute__((ext_vector_type(4))) unsigned short ushort4v;
typedef __attribute__((ext_vector_type(4))) float floatx4;

// fp32 -> bf16, round-to-nearest-even
__device__ __forceinline__ unsigned short f2b(float f) {
    union { float f; unsigned int u; } v; v.f = f;
    unsigned int u = v.u;
    unsigned int r = (u + 0x7fffu + ((u >> 16) & 1u)) >> 16;
    return (unsigned short)r;
}
// cheap round-half-up (for P weights; positive values)
__device__ __forceinline__ unsigned short f2b_fast(float f) {
    unsigned int u = __builtin_bit_cast(unsigned int, f);
    return (unsigned short)((u + 0x8000u) >> 16);
}

__device__ __forceinline__ void store_out(unsigned short* p, float v) { *p = f2b(v); }
__device__ __forceinline__ void store_out(float* p, float v) { *p = v; }

// async 16B global -> LDS (dest: wave-uniform base + lane*16)
__device__ __forceinline__ void async16(const unsigned short* g, unsigned short* lds) {
    __builtin_amdgcn_global_load_lds(
        (const __attribute__((address_space(1))) unsigned int*)g,
        (__attribute__((address_space(3))) unsigned int*)lds, 16, 0, 0);
}

// ---------------------------------------------------------------------------
// Prep kernel: blocks 0..2047 cast x fp32->bf16 (8 elems/thread);
// blocks 2048..3071 transpose+cast the two weight matrices (64x64 tiles).
// ---------------------------------------------------------------------------
__global__ __launch_bounds__(256) void prep_kernel(
    const float* __restrict__ x, unsigned short* __restrict__ xb,
    const float* __restrict__ Wqkv, const float* __restrict__ Wproj,
    unsigned short* __restrict__ Wqkv_t, unsigned short* __restrict__ Wproj_t)
{
    __shared__ float tile[64 * 65];
    const int tid = threadIdx.x;
    const int bid = blockIdx.x;

    if (bid < 2048) {                      // ---- cast x ----
        int i = bid * 256 + tid;
        const float4 v0 = *(const float4*)&x[(size_t)i * 8];
        const float4 v1 = *(const float4*)&x[(size_t)i * 8 + 4];
        ushort8 pk;
        pk[0] = f2b(v0.x); pk[1] = f2b(v0.y); pk[2] = f2b(v0.z); pk[3] = f2b(v0.w);
        pk[4] = f2b(v1.x); pk[5] = f2b(v1.y); pk[6] = f2b(v1.z); pk[7] = f2b(v1.w);
        *(ushort8*)&xb[(size_t)i * 8] = pk;
        return;
    }

    // ---- weight transposes ----
    const int xt = bid - 2048;             // 0..1023
    const int cxt = xt & 63;               // col-tile
    const int r0  = (xt >> 6) * 64;        // row-tile base
    const float* src; unsigned short* dst; int Ccols, c0;
    if (cxt < 48) { src = Wqkv;  dst = Wqkv_t;  Ccols = C3; c0 = cxt * 64; }
    else          { src = Wproj; dst = Wproj_t; Ccols = CC; c0 = (cxt - 48) * 64; }
#pragma unroll
    for (int it = 0; it < 4; it++) {
        int idx = it * 256 + tid;
        int row = idx >> 4;
        int c4  = idx & 15;
        float4 v = *(const float4*)&src[(size_t)(r0 + row) * Ccols + c0 + c4 * 4];
        tile[row * 65 + c4 * 4 + 0] = v.x;
        tile[row * 65 + c4 * 4 + 1] = v.y;
        tile[row * 65 + c4 * 4 + 2] = v.z;
        tile[row * 65 + c4 * 4 + 3] = v.w;
    }
    __syncthreads();
#pragma unroll
    for (int it = 0; it < 2; it++) {
        int idx = it * 256 + tid;
        int orow = idx >> 3;
        int o8   = idx & 7;
        ushort8 pk;
#pragma unroll
        for (int j = 0; j < 8; j++) pk[j] = f2b(tile[(o8 * 8 + j) * 65 + orow]);
        *(ushort8*)&dst[(size_t)(c0 + orow) * CC + r0 + o8 * 8] = pk;
    }
}

// ---------------------------------------------------------------------------
// Projection GEMM (R10, verified): 128x128 tile, BK=64, chunk-XOR swizzle,
// 8 waves (4M x 2N, acc[2][4]) -> 2 waves/SIMD.
// ---------------------------------------------------------------------------
template <typename OUT_T>
__global__ __launch_bounds__(512) void gemm_bt_kernel(
    const unsigned short* __restrict__ A, const unsigned short* __restrict__ Bm,
    const float* __restrict__ bias, OUT_T* __restrict__ Cmat,
    int M, int N, int K)
{
    __shared__ __align__(16) unsigned short sA[128 * 64];
    __shared__ __align__(16) unsigned short sB[128 * 64];

    const int tid = threadIdx.x;
    const int lane16 = tid & 15, quad = (tid & 63) >> 4;
    const int w = tid >> 6;                 // 0..7
    const int wm = w >> 1, wn = w & 1;      // 4M x 2N
    const int m0 = blockIdx.y * 128, n0 = blockIdx.x * 128;
    const int lx = lane16 & 7;

    floatx4 acc[2][4] = {};

    for (int kt = 0; kt < K; kt += 64) {
#pragma unroll
        for (int it = 0; it < 2; it++) {
            int idx = it * 512 + tid;
            int row = idx >> 3;
            int c8m = (idx & 7) ^ (row & 7);
            int wslot = it * 512 + (tid & 448);
            async16(&A[(size_t)(m0 + row) * K + kt + c8m * 8], &sA[wslot * 8]);
            async16(&Bm[(size_t)(n0 + row) * K + kt + c8m * 8], &sB[wslot * 8]);
        }
        __syncthreads();
#pragma unroll
        for (int ks = 0; ks < 2; ks++) {
            const int slot = (ks * 4 + quad) ^ lx;
            short8 af[2], bf[4];
#pragma unroll
            for (int t = 0; t < 2; t++)
                af[t] = *(const short8*)&sA[(wm * 32 + t * 16 + lane16) * 64 + slot * 8];
#pragma unroll
            for (int t = 0; t < 4; t++)
                bf[t] = *(const short8*)&sB[(wn * 64 + t * 16 + lane16) * 64 + slot * 8];
#pragma unroll
            for (int mt = 0; mt < 2; mt++)
#pragma unroll
                for (int nt = 0; nt < 4; nt++)
                    acc[mt][nt] = __builtin_amdgcn_mfma_f32_16x16x32_bf16(
                        af[mt], bf[nt], acc[mt][nt], 0, 0, 0);
        }
        __syncthreads();
    }

#pragma unroll
    for (int mt = 0; mt < 2; mt++) {
#pragma unroll
        for (int nt = 0; nt < 4; nt++) {
            int col = n0 + wn * 64 + nt * 16 + lane16;
            float bv = bias[col];
            int row0 = m0 + wm * 32 + mt * 16 + quad * 4;
#pragma unroll
            for (int r = 0; r < 4; r++)
                store_out(&Cmat[(size_t)(row0 + r) * N + col], acc[mt][nt][r] + bv);
        }
    }
}

// ---------------------------------------------------------------------------
// QKV GEMM, R12: BM=256 x BN=192, BK=64. Grid (3072/192=16, 4096/256=16) =
// 256 blocks = EXACTLY 1/CU (R9's 256^2 had 192 blocks -> 25% of CUs idle;
// measured R8 vs R9 showed per-block efficiency of the 256-wide pipeline is
// ~1.33x the 128^2's, cancelled by the idle CUs -- this shape keeps the
// pipeline AND the balance). 8 waves (2M x 4N; per-wave 128x48, acc[8][3]).
// LDS 112KB: sA 2x[256x64], sB 2x[192x64]. R9's verified schedule verbatim:
// 4 phases/tile, two raw s_barriers/tile, counted vmcnt (never 0 in main
// loop): 7 async16/thread/tile spread {2,2,2,1}; vmcnt(2) at phase 0 drains
// exactly the previous tile's 7 (oldest-first). FRAG epilogue unchanged
// (per-element col branch handles Q/K/V boundary straddling at n0 not
// 1024-aligned). Q pre-scaled by log2(e)/8.
// ---------------------------------------------------------------------------
__global__ __launch_bounds__(512, 2) void gemm256_frag_kernel(
    const unsigned short* __restrict__ A, const unsigned short* __restrict__ Bm,
    const float* __restrict__ bias,
    unsigned short* __restrict__ Qf, unsigned short* __restrict__ Kf,
    unsigned short* __restrict__ Vf, float qscale)
{
    // shorts: [0 .. 32768) sA[2][256*64] ; [32768 .. 57344) sB[2][192*64]
    __shared__ __align__(16) unsigned short sAB[57344];

    const int K = CC;                       // 1024
    const int NT = K / 64;                  // 16 K-tiles
    const int tid = threadIdx.x;
    const int lane16 = tid & 15, quad = (tid & 63) >> 4;
    const int w = tid >> 6;                 // 0..7
    const int wm = w >> 2, wn = w & 3;      // 2M x 4N
    const int m0 = blockIdx.y * 256, n0 = blockIdx.x * 192;
    const int lx = lane16 & 7;
    const int wbase = tid & 0x1C0;          // wave*64

    floatx4 acc[8][3] = {};

    // stage A-chunk q (q=0..3: rows [64q,64q+64)) of K-tile tn
    auto stageA = [&](int tn, int q, unsigned short* dA) {
        int idx = q * 512 + tid;
        int row = idx >> 3;
        int cc  = (idx & 7) ^ (row & 7);
        size_t koff = (size_t)tn * 64 + cc * 8;
        async16(&A[(size_t)(m0 + row) * K + koff], &dA[(q * 512 + wbase) * 8]);
    };
    // stage B-chunk q (q=0..2: rows [64q,64q+64)) of K-tile tn
    auto stageB = [&](int tn, int q, unsigned short* dB) {
        int idx = q * 512 + tid;
        int row = idx >> 3;
        int cc  = (idx & 7) ^ (row & 7);
        size_t koff = (size_t)tn * 64 + cc * 8;
        async16(&Bm[(size_t)(n0 + row) * K + koff], &dB[(q * 512 + wbase) * 8]);
    };

    // prologue: stage all of tile 0 (7 loads/thread)
    {
        unsigned short* dA = &sAB[0];
        unsigned short* dB = &sAB[32768];
#pragma unroll
        for (int q = 0; q < 4; q++) stageA(0, q, dA);
#pragma unroll
        for (int q = 0; q < 3; q++) stageB(0, q, dB);
    }

    for (int t = 0; t < NT; ++t) {
        const int pi = t & 1;
        unsigned short* sAc = &sAB[pi * 16384];
        unsigned short* sBc = &sAB[32768 + pi * 12288];
        unsigned short* sAn = &sAB[(pi ^ 1) * 16384];
        unsigned short* sBn = &sAB[32768 + (pi ^ 1) * 12288];
        const bool pre = (t + 1 < NT);

        // ---- phase 0 (mt = 0,1) ----
        if (pre) {
            stageA(t + 1, 0, sAn);
            stageA(t + 1, 1, sAn);
            asm volatile("s_waitcnt vmcnt(2)" ::: "memory");
        } else {
            asm volatile("s_waitcnt vmcnt(0)" ::: "memory");
        }
        __builtin_amdgcn_s_barrier();       // all waves: tile t landed

        short8 bf[3][2];
#pragma unroll
        for (int nt = 0; nt < 3; nt++)
#pragma unroll
            for (int ks = 0; ks < 2; ks++) {
                int r = wn * 48 + nt * 16 + lane16;
                int slot = (ks * 4 + quad) ^ lx;
                bf[nt][ks] = *(const short8*)&sBc[r * 64 + slot * 8];
            }
        {
            short8 af[2][2];
#pragma unroll
            for (int m2 = 0; m2 < 2; m2++)
#pragma unroll
                for (int ks = 0; ks < 2; ks++) {
                    int r = wm * 128 + m2 * 16 + lane16;
                    int slot = (ks * 4 + quad) ^ lx;
                    af[m2][ks] = *(const short8*)&sAc[r * 64 + slot * 8];
                }
            asm volatile("s_waitcnt lgkmcnt(0)" ::: "memory");
            __builtin_amdgcn_sched_barrier(0);
            __builtin_amdgcn_s_setprio(1);
#pragma unroll
            for (int m2 = 0; m2 < 2; m2++)
#pragma unroll
                for (int nt = 0; nt < 3; nt++)
#pragma unroll
                    for (int ks = 0; ks < 2; ks++)
                        acc[m2][nt] = __builtin_amdgcn_mfma_f32_16x16x32_bf16(
                            af[m2][ks], bf[nt][ks], acc[m2][nt], 0, 0, 0);
            __builtin_amdgcn_s_setprio(0);
        }

        // ---- phases 1..3 (mt = 2q, 2q+1) ----
#pragma unroll
        for (int q = 1; q < 4; q++) {
            if (pre) {
                if (q == 1) { stageA(t + 1, 2, sAn); stageA(t + 1, 3, sAn); }
                else if (q == 2) { stageB(t + 1, 0, sBn); stageB(t + 1, 1, sBn); }
                else { stageB(t + 1, 2, sBn); }
            }
            short8 af[2][2];
#pragma unroll
            for (int m2 = 0; m2 < 2; m2++)
#pragma unroll
                for (int ks = 0; ks < 2; ks++) {
                    int r = wm * 128 + (2 * q + m2) * 16 + lane16;
                    int slot = (ks * 4 + quad) ^ lx;
                    af[m2][ks] = *(const short8*)&sAc[r * 64 + slot * 8];
                }
            asm volatile("s_waitcnt lgkmcnt(0)" ::: "memory");
            __builtin_amdgcn_sched_barrier(0);
            __builtin_amdgcn_s_setprio(1);
#pragma unroll
            for (int m2 = 0; m2 < 2; m2++)
#pragma unroll
                for (int nt = 0; nt < 3; nt++)
#pragma unroll
                    for (int ks = 0; ks < 2; ks++)
                        acc[2 * q + m2][nt] = __builtin_amdgcn_mfma_f32_16x16x32_bf16(
                            af[m2][ks], bf[nt][ks], acc[2 * q + m2][nt], 0, 0, 0);
            __builtin_amdgcn_s_setprio(0);
        }

        __builtin_amdgcn_s_barrier();       // all reads of buf pi done
    }

    // ---- FRAG epilogue: Qf/Kf/Vf in MFMA-fragment order ----
#pragma unroll
    for (int mt = 0; mt < 8; mt++) {
#pragma unroll
        for (int nt = 0; nt < 3; nt++) {
            int col = n0 + wn * 48 + nt * 16 + lane16;
            float bv = bias[col];
            int row0 = m0 + wm * 128 + mt * 16 + quad * 4;
            const int breg = row0 >> 11;            // batch
            const int tok0 = row0 & (TT - 1);       // token (4-aligned)
            if (col < CC) {                          // ---- Q (scaled) ----
                int h = col >> 6, d = col & 63;
                int bh = breg * HH + h;
                size_t base = ((size_t)(bh * 128 + (tok0 >> 4)) * 2 + (d >> 5)) * 512
                            + ((d >> 3) & 3) * 128 + (tok0 & 15) * 8 + (d & 7);
#pragma unroll
                for (int r = 0; r < 4; r++)
                    Qf[base + r * 8] = f2b((acc[mt][nt][r] + bv) * qscale);
            } else if (col < 2 * CC) {               // ---- K ----
                int c = col - CC;
                int h = c >> 6, d = c & 63;
                int bh = breg * HH + h;
                size_t base = ((size_t)(bh * 128 + (tok0 >> 4)) * 2 + (d >> 5)) * 512
                            + ((d >> 3) & 3) * 128 + (tok0 & 15) * 8 + (d & 7);
#pragma unroll
                for (int r = 0; r < 4; r++)
                    Kf[base + r * 8] = f2b(acc[mt][nt][r] + bv);
            } else {                                 // ---- V ----
                int c = col - 2 * CC;
                int h = c >> 6, d = c & 63;
                int bh = breg * HH + h;
                size_t base = ((size_t)(bh * 64 + (tok0 >> 5)) * 4 + (d >> 4)) * 512
                            + (((tok0 >> 2) & 3) * 16 + (d & 15)) * 8
                            + ((tok0 >> 4) & 1) * 4;
                ushort4v pk;
#pragma unroll
                for (int r = 0; r < 4; r++) pk[r] = f2b(acc[mt][nt][r] + bv);
                *(ushort4v*)&Vf[base] = pk;
            }
        }
    }
}

// ---------------------------------------------------------------------------
// Flash attention (R8, verified): 4-wave block / 64-row q-tile, K/V staged
// per tile into LDS in fragment-chunk order via global_load_lds; lane-linear
// ds_read_b128 (zero bank conflicts); double-buffered, one barrier/tile.
// Swapped QK^T + in-register P. Grid (32 bh, 32 y), balanced p-map.
// ---------------------------------------------------------------------------
__global__ __launch_bounds__(256) void attn_mfma_kernel(
    const unsigned short* __restrict__ Qf, const unsigned short* __restrict__ Kf,
    const unsigned short* __restrict__ Vf, unsigned short* __restrict__ att)
{
    __shared__ __align__(16) unsigned short Ks[2][8 * 512];   // 8KB per buf
    __shared__ __align__(16) unsigned short Vs[2][8 * 512];   // 8KB per buf

    const int tid = threadIdx.x;
    const int l = tid & 63;
    const int w = tid >> 6;
    const int lane16 = l & 15, quad = l >> 4;
    const int bh = blockIdx.x;                    // same head -> same XCD
    const int b = bh >> 4, h = bh & 15;

    // balanced q-tile assignment (every CU's 4 blocks sum to 66 tile-units)
    const int y = blockIdx.y;                     // 0..31
    const int gcu = y & 7, s = y >> 3;
    const int p = 8 * s + ((s & 1) ? (7 - gcu) : gcu);
    const int q0 = p * 64;
    const int qw = q0 + w * 16;                   // this wave's 16 q-rows

    const unsigned short* Qb  = Qf + (size_t)bh * 131072 + l * 8;
    const unsigned short* KbT = Kf + (size_t)bh * 131072;
    const unsigned short* VbT = Vf + (size_t)bh * 131072;

    // Q fragments (B-operand layout: n=lane16=q, k=quad*8+j=d)
    short8 qf0 = *(const short8*)&Qb[(size_t)((qw >> 4) * 2 + 0) * 512];
    short8 qf1 = *(const short8*)&Qb[(size_t)((qw >> 4) * 2 + 1) * 512];

    floatx4 O[4] = {};                            // [dt]
    float ps = 0.f;                               // row-sum partial
    const int ntiles = p + 1;
    const int qrow = qw + lane16;                 // this lane's global q row

    // stage tile tt into LDS buffer buf: 16 chunks (K:0..7, V:8..15) split
    // 4 per wave; async16 dest = wave-uniform chunk base (+HW lane*16)
    auto stage = [&](int tt, int buf) {
#pragma unroll
        for (int s4 = 0; s4 < 4; s4++) {
            int c = s4 * 4 + w;
            if (c < 8)
                async16(&KbT[((size_t)tt * 8 + c) * 512 + l * 8], &Ks[buf][c * 512]);
            else
                async16(&VbT[((size_t)tt * 8 + (c - 8)) * 512 + l * 8], &Vs[buf][(c - 8) * 512]);
        }
    };

    stage(0, 0);
    __syncthreads();                              // drain stage of tile 0

    int cur = 0;
    for (int t = 0; t < ntiles; ++t) {
        if (t + 1 < ntiles) stage(t + 1, cur ^ 1);   // async into other buffer

        // ---- K fragments from LDS (lane-linear b128, conflict-free) ----
        short8 kf[8];
#pragma unroll
        for (int i = 0; i < 8; i++)
            kf[i] = *(const short8*)&Ks[cur][i * 512 + l * 8];

        // ---- S^T = K Q^T ; p = exp2(s); pack P as PV A-frag words ----
        const bool last = (t == ntiles - 1);
        short8 pa[2];                             // [kc]
#pragma unroll
        for (int nt = 0; nt < 4; nt++) {
            floatx4 s4v = {};
            s4v = __builtin_amdgcn_mfma_f32_16x16x32_bf16(kf[nt * 2 + 0], qf0, s4v, 0, 0, 0);
            s4v = __builtin_amdgcn_mfma_f32_16x16x32_bf16(kf[nt * 2 + 1], qf1, s4v, 0, 0, 0);
#pragma unroll
            for (int r = 0; r < 4; r++) {
                float v = s4v[r];
                if (last) {                       // diag tile: causal mask
                    int key = t * 64 + nt * 16 + quad * 4 + r;
                    if (key > qrow) v = -1e30f;
                }
                float pe = __builtin_amdgcn_exp2f(v);
                ps += pe;
                pa[nt >> 1][(nt & 1) * 4 + r] = (short)f2b_fast(pe);
            }
        }

        // ---- O += P V (V fragments from LDS, lane-linear b128) ----
#pragma unroll
        for (int kc = 0; kc < 2; kc++) {
            short8 vfr[4];
#pragma unroll
            for (int i = 0; i < 4; i++)
                vfr[i] = *(const short8*)&Vs[cur][(kc * 4 + i) * 512 + l * 8];
#pragma unroll
            for (int dt = 0; dt < 4; dt++)
                O[dt] = __builtin_amdgcn_mfma_f32_16x16x32_bf16(
                    pa[kc], vfr[dt], O[dt], 0, 0, 0);
        }

        __syncthreads();   // LDS reads done + next-tile stage drained (vmcnt)
        cur ^= 1;
    }

    // combine the 4 quads' row-sum partials (same lane16 = same q-row)
    ps += __shfl_xor(ps, 16, 64);
    ps += __shfl_xor(ps, 32, 64);

    unsigned short* ob = att + ((size_t)(b * TT) + qw) * CC + h * DD;
#pragma unroll
    for (int r = 0; r < 4; r++) {
        float rl = 1.0f / __shfl(ps, quad * 4 + r, 16);
        int q = quad * 4 + r;
#pragma unroll
        for (int dt = 0; dt < 4; dt++)
            ob[(size_t)q * CC + dt * 16 + lane16] = f2b(O[dt][r] * rl);
    }
}

// ---------------------------------------------------------------------------
extern "C" void kernel_launch(void* const* d_in, const int* in_sizes, int n_in,
                              void* d_out, int out_size, void* d_ws, size_t ws_size,
                              hipStream_t stream) {
    const float* x     = (const float*)d_in[0];
    const float* Wqkv  = (const float*)d_in[1];
    const float* bqkv  = (const float*)d_in[2];
    const float* Wproj = (const float*)d_in[3];
    const float* bproj = (const float*)d_in[4];
    float* out = (float*)d_out;

    const size_t FRAG_ELEMS = (size_t)128 * 2 * 512;             // 131072 per bh
    unsigned short* xb      = (unsigned short*)d_ws;             // [4096][1024]
    unsigned short* Qf      = xb + (size_t)BT * CC;              // [32][131072]
    unsigned short* Kf      = Qf + (size_t)BB * HH * FRAG_ELEMS;
    unsigned short* Vf      = Kf + (size_t)BB * HH * FRAG_ELEMS;
    unsigned short* Wqkv_t  = Vf + (size_t)BB * HH * FRAG_ELEMS; // [3072][1024]
    unsigned short* Wproj_t = Wqkv_t + (size_t)C3 * CC;          // [1024][1024]
    unsigned short* att_b   = Wproj_t + (size_t)CC * CC;         // [4096][1024]

    // 1) input cast + weight transposes (one launch)
    prep_kernel<<<3072, 256, 0, stream>>>(x, xb, Wqkv, Wproj, Wqkv_t, Wproj_t);

    // 2) QKV GEMM (256x192 8-wave, 256 blocks = 1/CU exact) -> Qf/Kf/Vf
    {
        dim3 grid(C3 / 192, BT / 256);   // 16 x 16 = 256 blocks
        gemm256_frag_kernel<<<grid, 512, 0, stream>>>(
            xb, Wqkv_t, bqkv, Qf, Kf, Vf, 0.125f * 1.44269504f);
    }
    // 3) flash attention (4-wave blocks, async fragment-chunk LDS staging)
    {
        dim3 grid(BB * HH, 32);
        attn_mfma_kernel<<<grid, 256, 0, stream>>>(Qf, Kf, Vf, att_b);
    }
    // 4) projection GEMM (8-wave 128^2, 2 waves/SIMD) -> fp32 out
    {
        dim3 grid(CC / 128, BT / 128);
        gemm_bt_kernel<float><<<grid, 512, 0, stream>>>(
            att_b, Wproj_t, bproj, out, BT, CC, CC);
    }
}